// Round 2
// baseline (1092.225 us; speedup 1.0000x reference)
//
#include <hip/hip_runtime.h>
#include <cstdint>
#include <cstddef>

#define LOG2E 1.442695040888963f

__device__ __forceinline__ float rdlane(float v, int lane) {
    return __int_as_float(__builtin_amdgcn_readlane(__float_as_int(v), lane));
}

template <int Q>
__device__ __forceinline__ float quad_bcast(float v) {
    // quad_perm broadcast of lane Q within each quad of 4 lanes
    return __int_as_float(__builtin_amdgcn_update_dpp(
        0, __float_as_int(v), Q * 0x55, 0xF, 0xF, true));
}

// proj[d][v][4j+g] = m(g) * (b[g*15+j] + W_ih[g*15+j,:] . emb[v,:])
__global__ __launch_bounds__(256) void proj_kernel(
    const float* __restrict__ emb,
    const float* __restrict__ w_ih_f, const float* __restrict__ b_f,
    const float* __restrict__ w_ih_b, const float* __restrict__ b_b,
    float* __restrict__ proj, int V) {
    int gid = blockIdx.x * 256 + threadIdx.x;
    int j = gid & 15;
    int rowid = gid >> 4;            // d*V + v
    if (j >= 15 || rowid >= 2 * V) return;
    int v = rowid % V;
    int d = rowid / V;
    const float* w  = d ? w_ih_b : w_ih_f;
    const float* bv = d ? b_b   : b_f;

    float x[15];
    #pragma unroll
    for (int k = 0; k < 15; ++k) x[k] = emb[v * 15 + k];

    float4 r;
    float* rp = &r.x;
    #pragma unroll
    for (int g = 0; g < 4; ++g) {
        int row = g * 15 + j;
        float acc = bv[row];
        #pragma unroll
        for (int k = 0; k < 15; ++k) acc = fmaf(x[k], w[row * 15 + k], acc);
        rp[g] = ((g == 2) ? (-2.0f * LOG2E) : (-LOG2E)) * acc;
    }
    *(float4*)(proj + (size_t)rowid * 64 + 4 * j) = r;
}

// One wave per sample b; the wave runs BOTH directions' chains interleaved
// (identical L), so each chain's dependency stalls are filled by the other
// chain's instructions. Lane = 4*j + g (g: 0=i 1=f 2=g 3=o).
__global__ __launch_bounds__(64) void lstm_kernel(
    const int* __restrict__ data, const int* __restrict__ lengths,
    const float* __restrict__ proj,
    const float* __restrict__ h0, const float* __restrict__ c0,
    const float* __restrict__ w_hh_f, const float* __restrict__ w_hh_b,
    float* __restrict__ out, int T, int V) {
    const int lane = threadIdx.x;
    const int b = blockIdx.x;
    const int L = lengths[b];

    if (lane >= 60) return;

    const int j = lane >> 2;
    const int g = lane & 3;
    const int row = g * 15 + j;
    const float K = -2.0f * LOG2E;
    const float mm = (g == 2) ? K : (-LOG2E);

    const bool gm0 = (g == 0), gm1 = (g == 1), gm2 = (g == 2), gm3 = (g == 3);

    float whA[15], whB[15];
    #pragma unroll
    for (int k = 0; k < 15; ++k) whA[k] = w_hh_f[row * 15 + k] * mm;
    #pragma unroll
    for (int k = 0; k < 15; ++k) whB[k] = w_hh_b[row * 15 + k] * mm;

    float hA = h0[b * 15 + j];
    float CA = K * c0[b * 15 + j];
    float hB = h0[(64 + b) * 15 + j];
    float CB = K * c0[(64 + b) * 15 + j];

    const int* drow = data + (size_t)b * T;
    const float* pjA = proj + lane;
    const float* pjB = proj + (size_t)V * 64 + lane;

    float* wpA = out + ((size_t)b * T + (size_t)g) * 45 + j;
    float* wpB = out + ((size_t)b * T + (size_t)(L - 1 - g)) * 45 + 15 + j;
    float* outpA = out + ((size_t)b * T) * 45 + j;
    float* outpB = out + ((size_t)b * T) * 45 + 15 + j;

    auto tokA = [&](int t) -> int {
        int tt = t < L ? t : L - 1;
        return drow[tt];
    };
    auto tokB = [&](int t) -> int {
        int tt = t < L ? t : L - 1;
        return drow[L - 1 - tt];
    };

    // One fused round: advances chain A and chain B one step each,
    // instruction-zipped so each chain's stalls hide under the other.
    auto step2 = [&](float xgA, float xgB) {
        float A0 = rdlane(hA, 0),  A1 = rdlane(hA, 4),  A2 = rdlane(hA, 8);
        float A3 = rdlane(hA, 12), A4 = rdlane(hA, 16), A5 = rdlane(hA, 20);
        float A6 = rdlane(hA, 24), A7 = rdlane(hA, 28), A8 = rdlane(hA, 32);
        float A9 = rdlane(hA, 36), A10 = rdlane(hA, 40), A11 = rdlane(hA, 44);
        float A12 = rdlane(hA, 48), A13 = rdlane(hA, 52), A14 = rdlane(hA, 56);
        float B0 = rdlane(hB, 0),  B1 = rdlane(hB, 4),  B2 = rdlane(hB, 8);
        float B3 = rdlane(hB, 12), B4 = rdlane(hB, 16), B5 = rdlane(hB, 20);
        float B6 = rdlane(hB, 24), B7 = rdlane(hB, 28), B8 = rdlane(hB, 32);
        float B9 = rdlane(hB, 36), B10 = rdlane(hB, 40), B11 = rdlane(hB, 44);
        float B12 = rdlane(hB, 48), B13 = rdlane(hB, 52), B14 = rdlane(hB, 56);

        float aA0 = xgA, aA1 = 0.f, aA2 = 0.f, aA3 = 0.f;
        float aB0 = xgB, aB1 = 0.f, aB2 = 0.f, aB3 = 0.f;
        aA0 = fmaf(A0,  whA[0],  aA0);  aB0 = fmaf(B0,  whB[0],  aB0);
        aA1 = fmaf(A1,  whA[1],  aA1);  aB1 = fmaf(B1,  whB[1],  aB1);
        aA2 = fmaf(A2,  whA[2],  aA2);  aB2 = fmaf(B2,  whB[2],  aB2);
        aA3 = fmaf(A3,  whA[3],  aA3);  aB3 = fmaf(B3,  whB[3],  aB3);
        aA0 = fmaf(A4,  whA[4],  aA0);  aB0 = fmaf(B4,  whB[4],  aB0);
        aA1 = fmaf(A5,  whA[5],  aA1);  aB1 = fmaf(B5,  whB[5],  aB1);
        aA2 = fmaf(A6,  whA[6],  aA2);  aB2 = fmaf(B6,  whB[6],  aB2);
        aA3 = fmaf(A7,  whA[7],  aA3);  aB3 = fmaf(B7,  whB[7],  aB3);
        aA0 = fmaf(A8,  whA[8],  aA0);  aB0 = fmaf(B8,  whB[8],  aB0);
        aA1 = fmaf(A9,  whA[9],  aA1);  aB1 = fmaf(B9,  whB[9],  aB1);
        aA2 = fmaf(A10, whA[10], aA2);  aB2 = fmaf(B10, whB[10], aB2);
        aA3 = fmaf(A11, whA[11], aA3);  aB3 = fmaf(B11, whB[11], aB3);
        aA0 = fmaf(A12, whA[12], aA0);  aB0 = fmaf(B12, whB[12], aB0);
        aA1 = fmaf(A13, whA[13], aA1);  aB1 = fmaf(B13, whB[13], aB1);
        float sA = (aA0 + aA1) + (aA2 + aA3);
        float sB = (aB0 + aB1) + (aB2 + aB3);
        float zA = fmaf(A14, whA[14], sA);
        float zB = fmaf(B14, whB[14], sB);
        float eA = __builtin_amdgcn_exp2f(zA);
        float eB = __builtin_amdgcn_exp2f(zB);
        float wA = __builtin_amdgcn_rcpf(1.0f + eA);
        float wB = __builtin_amdgcn_rcpf(1.0f + eB);
        float wfA = quad_bcast<1>(wA);        // f first: on the C critical path
        float wfB = quad_bcast<1>(wB);
        float wiA = quad_bcast<0>(wA);
        float wiB = quad_bcast<0>(wB);
        float wgA = quad_bcast<2>(wA);
        float wgB = quad_bcast<2>(wB);
        float woA = quad_bcast<3>(wA);
        float woB = quad_bcast<3>(wB);
        float tgA = fmaf(2.0f * K, wgA, -K);  // K * tanh(z_g)
        float tgB = fmaf(2.0f * K, wgB, -K);
        CA = fmaf(wfA, CA, wiA * tgA);        // C = -2log2e * c
        CB = fmaf(wfB, CB, wiB * tgB);
        float ecA = __builtin_amdgcn_exp2f(CA);
        float ecB = __builtin_amdgcn_exp2f(CB);
        float wcA = __builtin_amdgcn_rcpf(1.0f + ecA);
        float wcB = __builtin_amdgcn_rcpf(1.0f + ecB);
        hA = fmaf(woA + woA, wcA, -woA);      // vo * tanh(c)
        hB = fmaf(woB + woB, wcB, -woB);
    };

    float a0[8], a1[8], b0[8], b1[8];
    int taA[8], tbA[8], taB[8], tbB[8];

    #pragma unroll
    for (int u = 0; u < 8; ++u) taA[u] = tokA(u);
    #pragma unroll
    for (int u = 0; u < 8; ++u) a0[u] = pjA[(size_t)taA[u] * 64];
    #pragma unroll
    for (int u = 0; u < 8; ++u) taA[u] = tokA(8 + u);
    #pragma unroll
    for (int u = 0; u < 8; ++u) a1[u] = pjA[(size_t)taA[u] * 64];
    #pragma unroll
    for (int u = 0; u < 8; ++u) taB[u] = tokB(u);
    #pragma unroll
    for (int u = 0; u < 8; ++u) b0[u] = pjB[(size_t)taB[u] * 64];
    #pragma unroll
    for (int u = 0; u < 8; ++u) taB[u] = tokB(8 + u);
    #pragma unroll
    for (int u = 0; u < 8; ++u) b1[u] = pjB[(size_t)taB[u] * 64];
    #pragma unroll
    for (int u = 0; u < 8; ++u) taA[u] = tokA(16 + u);
    #pragma unroll
    for (int u = 0; u < 8; ++u) tbA[u] = tokA(24 + u);
    #pragma unroll
    for (int u = 0; u < 8; ++u) taB[u] = tokB(16 + u);
    #pragma unroll
    for (int u = 0; u < 8; ++u) tbB[u] = tokB(24 + u);

    auto halfrun2 = [&](float (&xa)[8], int (&tka)[8],
                        float (&xb)[8], int (&tkb)[8], int th) {
        float hcA = hA, hcB = hB;
        step2(xa[0], xb[0]); hcA = gm0 ? hA : hcA; hcB = gm0 ? hB : hcB;
        step2(xa[1], xb[1]); hcA = gm1 ? hA : hcA; hcB = gm1 ? hB : hcB;
        step2(xa[2], xb[2]); hcA = gm2 ? hA : hcA; hcB = gm2 ? hB : hcB;
        step2(xa[3], xb[3]); hcA = gm3 ? hA : hcA; hcB = gm3 ? hB : hcB;
        __builtin_nontemporal_store(hcA, wpA + (ptrdiff_t)th * 45);
        __builtin_nontemporal_store(hcB, wpB - (ptrdiff_t)th * 45);
        step2(xa[4], xb[4]); hcA = gm0 ? hA : hcA; hcB = gm0 ? hB : hcB;
        step2(xa[5], xb[5]); hcA = gm1 ? hA : hcA; hcB = gm1 ? hB : hcB;
        step2(xa[6], xb[6]); hcA = gm2 ? hA : hcA; hcB = gm2 ? hB : hcB;
        step2(xa[7], xb[7]); hcA = gm3 ? hA : hcA; hcB = gm3 ? hB : hcB;
        __builtin_nontemporal_store(hcA, wpA + (ptrdiff_t)(th + 4) * 45);
        __builtin_nontemporal_store(hcB, wpB - (ptrdiff_t)(th + 4) * 45);
        #pragma unroll
        for (int u = 0; u < 8; ++u) xa[u] = pjA[(size_t)tka[u] * 64];
        #pragma unroll
        for (int u = 0; u < 8; ++u) xb[u] = pjB[(size_t)tkb[u] * 64];
        #pragma unroll
        for (int u = 0; u < 8; ++u) tka[u] = tokA(th + 32 + u);
        #pragma unroll
        for (int u = 0; u < 8; ++u) tkb[u] = tokB(th + 32 + u);
    };

    int t = 0;
    for (; t + 16 <= L; t += 16) {
        halfrun2(a0, taA, b0, taB, t);
        halfrun2(a1, tbA, b1, tbB, t + 8);
    }
    #pragma unroll 1
    for (int u = 0; u < 8 && t < L; ++u, ++t) {
        step2(a0[u], b0[u]);
        outpA[(size_t)t * 45] = hA;
        outpB[(size_t)(L - 1 - t) * 45] = hB;
    }
    #pragma unroll 1
    for (int u = 0; u < 8 && t < L; ++u, ++t) {
        step2(a1[u], b1[u]);
        outpA[(size_t)t * 45] = hA;
        outpB[(size_t)(L - 1 - t) * 45] = hB;
    }
}

// Epilogue: in-place linear 30 -> 45 per (b,t) row; t >= L rows get lin_b.
__global__ __launch_bounds__(256) void linear_kernel(
    const int* __restrict__ lengths,
    const float* __restrict__ lin_w, const float* __restrict__ lin_b,
    float* out, int T) {
    __shared__ float Ws[45 * 30];
    __shared__ float Bs[45];
    for (int i = threadIdx.x; i < 45 * 30; i += 256) Ws[i] = lin_w[i];
    if (threadIdx.x < 45) Bs[threadIdx.x] = lin_b[threadIdx.x];
    __syncthreads();
    const int b = blockIdx.y;
    const int t = blockIdx.x * 256 + threadIdx.x;
    if (t >= T) return;
    const int L = lengths[b];
    float* row = out + ((size_t)b * T + t) * 45;
    float y[45];
    if (t < L) {
        float x[30];
        #pragma unroll
        for (int k = 0; k < 30; ++k) x[k] = row[k];
        #pragma unroll
        for (int o = 0; o < 45; ++o) {
            float acc = Bs[o];
            #pragma unroll
            for (int k = 0; k < 30; ++k) acc = fmaf(x[k], Ws[o * 30 + k], acc);
            y[o] = acc;
        }
    } else {
        #pragma unroll
        for (int o = 0; o < 45; ++o) y[o] = Bs[o];
    }
    #pragma unroll
    for (int o = 0; o < 45; ++o) row[o] = y[o];
}

extern "C" void kernel_launch(void* const* d_in, const int* in_sizes, int n_in,
                              void* d_out, int out_size, void* d_ws, size_t ws_size,
                              hipStream_t stream) {
    const int* data      = (const int*)d_in[0];
    const int* lengths   = (const int*)d_in[2];
    const float* emb     = (const float*)d_in[3];
    const float* h0      = (const float*)d_in[4];
    const float* c0      = (const float*)d_in[5];
    const float* w_ih_f  = (const float*)d_in[6];
    const float* w_hh_f  = (const float*)d_in[7];
    const float* b_f     = (const float*)d_in[8];
    const float* w_ih_b  = (const float*)d_in[9];
    const float* w_hh_b  = (const float*)d_in[10];
    const float* b_b     = (const float*)d_in[11];
    const float* lin_w   = (const float*)d_in[12];
    const float* lin_b   = (const float*)d_in[13];
    float* out = (float*)d_out;

    const int T = in_sizes[0] / 64;
    const int V = in_sizes[3] / 15;
    float* proj = (float*)d_ws;   // 2*V*64 floats = 25.6 MB

    hipLaunchKernelGGL(proj_kernel, dim3((2 * V * 16 + 255) / 256), dim3(256), 0, stream,
                       emb, w_ih_f, b_f, w_ih_b, b_b, proj, V);
    hipLaunchKernelGGL(lstm_kernel, dim3(64), dim3(64), 0, stream,
                       data, lengths, proj, h0, c0, w_hh_f, w_hh_b, out, T, V);
    hipLaunchKernelGGL(linear_kernel, dim3((T + 255) / 256, 64), dim3(256), 0, stream,
                       lengths, lin_w, lin_b, out, T);
}

// Round 3
// 640.918 us; speedup vs baseline: 1.7042x; 1.7042x over previous
//
#include <hip/hip_runtime.h>
#include <cstdint>
#include <cstddef>

#define LOG2E 1.442695040888963f

__device__ __forceinline__ float rdlane(float v, int lane) {
    return __int_as_float(__builtin_amdgcn_readlane(__float_as_int(v), lane));
}

template <int Q>
__device__ __forceinline__ float quad_bcast(float v) {
    // quad_perm broadcast of lane Q within each quad of 4 lanes
    return __int_as_float(__builtin_amdgcn_update_dpp(
        0, __float_as_int(v), Q * 0x55, 0xF, 0xF, true));
}

typedef float v2f __attribute__((ext_vector_type(2)));

union pf2 {
    float f[2];
    unsigned long long u;
};

// proj[d][v][4j+g] = m(g) * (b[g*15+j] + W_ih[g*15+j,:] . emb[v,:])
__global__ __launch_bounds__(256) void proj_kernel(
    const float* __restrict__ emb,
    const float* __restrict__ w_ih_f, const float* __restrict__ b_f,
    const float* __restrict__ w_ih_b, const float* __restrict__ b_b,
    float* __restrict__ proj, int V) {
    int gid = blockIdx.x * 256 + threadIdx.x;
    int j = gid & 15;
    int rowid = gid >> 4;            // d*V + v
    if (j >= 15 || rowid >= 2 * V) return;
    int v = rowid % V;
    int d = rowid / V;
    const float* w  = d ? w_ih_b : w_ih_f;
    const float* bv = d ? b_b   : b_f;

    float x[15];
    #pragma unroll
    for (int k = 0; k < 15; ++k) x[k] = emb[v * 15 + k];

    float4 r;
    float* rp = &r.x;
    #pragma unroll
    for (int g = 0; g < 4; ++g) {
        int row = g * 15 + j;
        float acc = bv[row];
        #pragma unroll
        for (int k = 0; k < 15; ++k) acc = fmaf(x[k], w[row * 15 + k], acc);
        rp[g] = ((g == 2) ? (-2.0f * LOG2E) : (-LOG2E)) * acc;
    }
    *(float4*)(proj + (size_t)rowid * 64 + 4 * j) = r;
}

// One wave per (direction, sample). Lane = 4*j + g (g: 0=i 1=f 2=g 3=o).
// R1-proven structure; h.W_hh dot compressed with v_pk_fma_f32:
// 15 readlanes pair into 7 SGPR pairs feeding packed FMAs (single-wave issue
// cadence ~5cy/instr makes instruction count the only lever).
__global__ __launch_bounds__(64) void lstm_kernel(
    const int* __restrict__ data, const int* __restrict__ lengths,
    const float* __restrict__ proj,
    const float* __restrict__ h0, const float* __restrict__ c0,
    const float* __restrict__ w_hh_f, const float* __restrict__ w_hh_b,
    float* __restrict__ out, int T, int V) {
    const int lane = threadIdx.x;
    const int dir = blockIdx.x >> 6;
    const int b = blockIdx.x & 63;
    const int L = lengths[b];

    if (lane >= 60) return;

    const int j = lane >> 2;
    const int g = lane & 3;
    const int row = g * 15 + j;
    const float K = -2.0f * LOG2E;

    const float* whh = dir ? w_hh_b : w_hh_f;
    const float mm = (g == 2) ? K : (-LOG2E);

    const bool gm0 = (g == 0), gm1 = (g == 1), gm2 = (g == 2), gm3 = (g == 3);

    // weights pre-paired for packed FMA: whp[i] = (wh[2i], wh[2i+1]), + wh14
    v2f whp[7];
    #pragma unroll
    for (int i = 0; i < 7; ++i) {
        whp[i].x = whh[row * 15 + 2 * i] * mm;
        whp[i].y = whh[row * 15 + 2 * i + 1] * mm;
    }
    float wh14 = whh[row * 15 + 14] * mm;

    float h = h0[(dir * 64 + b) * 15 + j];        // replicated across quad
    float C = K * c0[(dir * 64 + b) * 15 + j];    // pre-scaled cell state

    const int* drow = data + (size_t)b * T;
    const float* pj = proj + (size_t)dir * V * 64 + lane;
    const int sgn  = dir ? -1 : 1;
    const int base = dir ? (L - 1) : 0;

    float* wp = out + ((size_t)b * T + (size_t)(dir ? (L - 1 - g) : g)) * 45 + dir * 15 + j;
    float* outp = out + ((size_t)b * T) * 45 + dir * 15 + j;

    auto tok = [&](int t) -> int {
        int tt = t < L ? t : L - 1;
        return drow[base + sgn * tt];
    };

    auto step = [&](float xg) {
        pf2 hp0, hp1, hp2, hp3, hp4, hp5, hp6;
        hp0.f[0] = rdlane(h, 0);  hp0.f[1] = rdlane(h, 4);
        hp1.f[0] = rdlane(h, 8);  hp1.f[1] = rdlane(h, 12);
        hp2.f[0] = rdlane(h, 16); hp2.f[1] = rdlane(h, 20);
        hp3.f[0] = rdlane(h, 24); hp3.f[1] = rdlane(h, 28);
        hp4.f[0] = rdlane(h, 32); hp4.f[1] = rdlane(h, 36);
        hp5.f[0] = rdlane(h, 40); hp5.f[1] = rdlane(h, 44);
        hp6.f[0] = rdlane(h, 48); hp6.f[1] = rdlane(h, 52);
        float hk14 = rdlane(h, 56);
        v2f acc;
        acc.x = xg; acc.y = 0.0f;
        asm("v_pk_fma_f32 %0, %1, %2, %0" : "+v"(acc) : "s"(hp0.u), "v"(whp[0]));
        asm("v_pk_fma_f32 %0, %1, %2, %0" : "+v"(acc) : "s"(hp1.u), "v"(whp[1]));
        asm("v_pk_fma_f32 %0, %1, %2, %0" : "+v"(acc) : "s"(hp2.u), "v"(whp[2]));
        asm("v_pk_fma_f32 %0, %1, %2, %0" : "+v"(acc) : "s"(hp3.u), "v"(whp[3]));
        asm("v_pk_fma_f32 %0, %1, %2, %0" : "+v"(acc) : "s"(hp4.u), "v"(whp[4]));
        asm("v_pk_fma_f32 %0, %1, %2, %0" : "+v"(acc) : "s"(hp5.u), "v"(whp[5]));
        asm("v_pk_fma_f32 %0, %1, %2, %0" : "+v"(acc) : "s"(hp6.u), "v"(whp[6]));
        float s = acc.x + acc.y;
        float z = fmaf(hk14, wh14, s);
        float w = __builtin_amdgcn_rcpf(1.0f + __builtin_amdgcn_exp2f(z));
        float wf = quad_bcast<1>(w);          // f first: on the C critical path
        float wi = quad_bcast<0>(w);
        float wg = quad_bcast<2>(w);
        float wo = quad_bcast<3>(w);
        float tg2 = fmaf(2.0f * K, wg, -K);   // K * tanh(z_g)
        C = fmaf(wf, C, wi * tg2);            // C = -2log2e * c
        float wc = __builtin_amdgcn_rcpf(1.0f + __builtin_amdgcn_exp2f(C));
        float p2 = wo + wo;
        h = fmaf(p2, wc, -wo);                // vo * tanh(c), replicated in quad
    };

    float xA[8], xB[8];
    int ta[8], tb[8];

    #pragma unroll
    for (int u = 0; u < 8; ++u) ta[u] = tok(u);
    #pragma unroll
    for (int u = 0; u < 8; ++u) xA[u] = pj[(size_t)ta[u] * 64];
    #pragma unroll
    for (int u = 0; u < 8; ++u) ta[u] = tok(8 + u);
    #pragma unroll
    for (int u = 0; u < 8; ++u) xB[u] = pj[(size_t)ta[u] * 64];
    #pragma unroll
    for (int u = 0; u < 8; ++u) ta[u] = tok(16 + u);
    #pragma unroll
    for (int u = 0; u < 8; ++u) tb[u] = tok(24 + u);

    auto halfrun = [&](float (&xb)[8], int (&tkb)[8], int th) {
        float hc = h;
        step(xb[0]); hc = gm0 ? h : hc;
        step(xb[1]); hc = gm1 ? h : hc;
        step(xb[2]); hc = gm2 ? h : hc;
        step(xb[3]); hc = gm3 ? h : hc;
        __builtin_nontemporal_store(hc, wp + (ptrdiff_t)sgn * th * 45);
        step(xb[4]); hc = gm0 ? h : hc;
        step(xb[5]); hc = gm1 ? h : hc;
        step(xb[6]); hc = gm2 ? h : hc;
        step(xb[7]); hc = gm3 ? h : hc;
        __builtin_nontemporal_store(hc, wp + (ptrdiff_t)sgn * (th + 4) * 45);
        #pragma unroll
        for (int u = 0; u < 8; ++u) xb[u] = pj[(size_t)tkb[u] * 64];
        #pragma unroll
        for (int u = 0; u < 8; ++u) tkb[u] = tok(th + 32 + u);
    };

    int t = 0;
    for (; t + 16 <= L; t += 16) {
        halfrun(xA, ta, t);
        halfrun(xB, tb, t + 8);
    }
    #pragma unroll 1
    for (int u = 0; u < 8 && t < L; ++u, ++t) {
        step(xA[u]);
        outp[(size_t)(base + sgn * t) * 45] = h;
    }
    #pragma unroll 1
    for (int u = 0; u < 8 && t < L; ++u, ++t) {
        step(xB[u]);
        outp[(size_t)(base + sgn * t) * 45] = h;
    }
}

// Epilogue: in-place linear 30 -> 45 per (b,t) row; t >= L rows get lin_b.
__global__ __launch_bounds__(256) void linear_kernel(
    const int* __restrict__ lengths,
    const float* __restrict__ lin_w, const float* __restrict__ lin_b,
    float* out, int T) {
    __shared__ float Ws[45 * 30];
    __shared__ float Bs[45];
    for (int i = threadIdx.x; i < 45 * 30; i += 256) Ws[i] = lin_w[i];
    if (threadIdx.x < 45) Bs[threadIdx.x] = lin_b[threadIdx.x];
    __syncthreads();
    const int b = blockIdx.y;
    const int t = blockIdx.x * 256 + threadIdx.x;
    if (t >= T) return;
    const int L = lengths[b];
    float* row = out + ((size_t)b * T + t) * 45;
    float y[45];
    if (t < L) {
        float x[30];
        #pragma unroll
        for (int k = 0; k < 30; ++k) x[k] = row[k];
        #pragma unroll
        for (int o = 0; o < 45; ++o) {
            float acc = Bs[o];
            #pragma unroll
            for (int k = 0; k < 30; ++k) acc = fmaf(x[k], Ws[o * 30 + k], acc);
            y[o] = acc;
        }
    } else {
        #pragma unroll
        for (int o = 0; o < 45; ++o) y[o] = Bs[o];
    }
    #pragma unroll
    for (int o = 0; o < 45; ++o) row[o] = y[o];
}

extern "C" void kernel_launch(void* const* d_in, const int* in_sizes, int n_in,
                              void* d_out, int out_size, void* d_ws, size_t ws_size,
                              hipStream_t stream) {
    const int* data      = (const int*)d_in[0];
    const int* lengths   = (const int*)d_in[2];
    const float* emb     = (const float*)d_in[3];
    const float* h0      = (const float*)d_in[4];
    const float* c0      = (const float*)d_in[5];
    const float* w_ih_f  = (const float*)d_in[6];
    const float* w_hh_f  = (const float*)d_in[7];
    const float* b_f     = (const float*)d_in[8];
    const float* w_ih_b  = (const float*)d_in[9];
    const float* w_hh_b  = (const float*)d_in[10];
    const float* b_b     = (const float*)d_in[11];
    const float* lin_w   = (const float*)d_in[12];
    const float* lin_b   = (const float*)d_in[13];
    float* out = (float*)d_out;

    const int T = in_sizes[0] / 64;
    const int V = in_sizes[3] / 15;
    float* proj = (float*)d_ws;   // 2*V*64 floats = 25.6 MB

    hipLaunchKernelGGL(proj_kernel, dim3((2 * V * 16 + 255) / 256), dim3(256), 0, stream,
                       emb, w_ih_f, b_f, w_ih_b, b_b, proj, V);
    hipLaunchKernelGGL(lstm_kernel, dim3(128), dim3(64), 0, stream,
                       data, lengths, proj, h0, c0, w_hh_f, w_hh_b, out, T, V);
    hipLaunchKernelGGL(linear_kernel, dim3((T + 255) / 256, 64), dim3(256), 0, stream,
                       lengths, lin_w, lin_b, out, T);
}